// Round 1
// baseline (320.608 us; speedup 1.0000x reference)
//
#include <hip/hip_runtime.h>
#include <stdint.h>

#define H_   2048
#define NH   16
#define HD   128
#define B_   2
#define S_   2048
#define NR   (B_*S_)        // 4096 rows of x
#define NQKV (H_ + 2*HD)    // 2304 fused QKV output cols

typedef __attribute__((ext_vector_type(8))) short bf16x8;
typedef __attribute__((ext_vector_type(4))) float f32x4;
typedef __attribute__((ext_vector_type(4))) unsigned short u16x4;

#define MFMA(a,b,c) __builtin_amdgcn_mfma_f32_16x16x32_bf16(a,b,c,0,0,0)

__device__ __forceinline__ unsigned short f2bf(float f){
  union{ float f; unsigned int u; } v; v.f = f;
  unsigned int u = v.u;
  return (unsigned short)((u + 0x7fffu + ((u>>16)&1u)) >> 16);
}

__device__ __forceinline__ void gl_lds16(const void* g, void* l){
  __builtin_amdgcn_global_load_lds((const __attribute__((address_space(1))) void*)g,
                                   (__attribute__((address_space(3))) void*)l, 16, 0, 0);
}

// ---------- fp32 -> bf16 convert (x) ----------
__global__ __launch_bounds__(256) void k_convx(const float* __restrict__ x,
                                               unsigned short* __restrict__ xb){
  long i = ((long)blockIdx.x*256 + threadIdx.x)*4;
  float4 f = *reinterpret_cast<const float4*>(x + i);
  u16x4 o;
  o[0]=f2bf(f.x); o[1]=f2bf(f.y); o[2]=f2bf(f.z); o[3]=f2bf(f.w);
  *reinterpret_cast<u16x4*>(xb + i) = o;
}

// ---------- transpose-convert W [K=2048][N] f32 -> Bt rows [rowoff..rowoff+N) pitch 2048 bf16 ----------
__global__ __launch_bounds__(256) void k_transw(const float* __restrict__ W,
                                                unsigned short* __restrict__ Bt,
                                                int N, int rowoff){
  __shared__ float t[32][33];
  int n0 = blockIdx.x*32, k0 = blockIdx.y*32;
  int tx = threadIdx.x & 31, ty = threadIdx.x >> 5;  // ty 0..7
  #pragma unroll
  for(int r=0;r<32;r+=8) t[ty+r][tx] = W[(long)(k0+ty+r)*N + n0+tx];
  __syncthreads();
  #pragma unroll
  for(int r=0;r<32;r+=8)
    Bt[(long)(rowoff + n0+ty+r)*2048 + k0+tx] = f2bf(t[tx][ty+r]);
}

// ---------- concat bias [bq|bk|bv] -> f32[2304] ----------
__global__ void k_biascat(const float* __restrict__ bq, const float* __restrict__ bk,
                          const float* __restrict__ bv, float* __restrict__ o){
  int t = blockIdx.x*256 + threadIdx.x;
  if(t < H_) o[t] = bq[t];
  else if(t < H_+HD) o[t] = bk[t-H_];
  else o[t] = bv[t-H_-HD];
}

// ---------- bf16 transpose of V columns of QKV -> Vtg [B][128][2048] ----------
__global__ __launch_bounds__(256) void k_transv(const unsigned short* __restrict__ QKV,
                                                unsigned short* __restrict__ Vtg){
  __shared__ unsigned short t[32][33];
  int s0 = blockIdx.x*32, d0 = blockIdx.y*32, z = blockIdx.z;
  int tx = threadIdx.x & 31, ty = threadIdx.x >> 5;
  #pragma unroll
  for(int r=0;r<32;r+=8)
    t[ty+r][tx] = QKV[(long)(z*S_ + s0+ty+r)*NQKV + (H_+HD) + d0+tx];
  __syncthreads();
  #pragma unroll
  for(int r=0;r<32;r+=8)
    Vtg[(long)z*HD*S_ + (long)(d0+ty+r)*S_ + s0+tx] = t[tx][ty+r];
}

// ---------- bf16 GEMM: A[M][K] row-major, Bt[N][K] row-major, +bias, m97-style 128x128 ----------
template<int OUT_BF16>
__global__ __launch_bounds__(256) void k_gemm(const unsigned short* __restrict__ A,
                                              const unsigned short* __restrict__ Bt,
                                              const float* __restrict__ bias,
                                              void* __restrict__ out,
                                              int M, int N, int K){
  __shared__ unsigned short lA[2][128*32];
  __shared__ unsigned short lB[2][128*32];
  const int tid = threadIdx.x, lane = tid & 63, w = tid >> 6;
  const int wr = w >> 1, wc = w & 1;
  const long bm = (long)blockIdx.y*128, bn = (long)blockIdx.x*128;
  const int rl = lane & 15, rh = lane >> 4;
  f32x4 acc[4][4] = {};

  // staging geometry: instruction q of wave w covers LDS elems [(w*2+q)*512, +512)
  // lane -> row (w*2+q)*16 + lane/4, col chunk (lane&3); source chunk pre-swizzled (involution)
  const int srow = lane >> 2;
  const int scb  = (((lane&3) ^ ((lane>>2)&3)) * 8);  // element offset within BK=32
  long arow[2], brow[2];
  #pragma unroll
  for(int q=0;q<2;q++){ arow[q] = bm + (w*2+q)*16 + srow; brow[q] = bn + (w*2+q)*16 + srow; }

  const int nk = K >> 5;
  #pragma unroll
  for(int q=0;q<2;q++){
    gl_lds16(A  + arow[q]*K + scb, &lA[0][(w*2+q)*512]);
    gl_lds16(Bt + brow[q]*K + scb, &lB[0][(w*2+q)*512]);
  }
  __syncthreads();

  for(int kt=0; kt<nk; ++kt){
    const int cur = kt & 1;
    if(kt+1 < nk){
      const int k0 = (kt+1) << 5;
      #pragma unroll
      for(int q=0;q<2;q++){
        gl_lds16(A  + arow[q]*K + k0 + scb, &lA[cur^1][(w*2+q)*512]);
        gl_lds16(Bt + brow[q]*K + k0 + scb, &lB[cur^1][(w*2+q)*512]);
      }
    }
    bf16x8 af[4], bfr[4];
    #pragma unroll
    for(int i=0;i<4;i++){
      int ra = wr*64 + i*16 + rl;
      af[i]  = *(const bf16x8*)((const char*)&lA[cur][0] + ra*64 + ((rh*16) ^ ((rl&3)<<4)));
      int rb = wc*64 + i*16 + rl;
      bfr[i] = *(const bf16x8*)((const char*)&lB[cur][0] + rb*64 + ((rh*16) ^ ((rl&3)<<4)));
    }
    #pragma unroll
    for(int i=0;i<4;i++)
      #pragma unroll
      for(int j=0;j<4;j++)
        acc[i][j] = MFMA(af[i], bfr[j], acc[i][j]);
    __syncthreads();
  }

  #pragma unroll
  for(int j=0;j<4;j++){
    long col = bn + wc*64 + j*16 + rl;
    float bb = bias[col];
    #pragma unroll
    for(int i=0;i<4;i++){
      long row = bm + wr*64 + i*16 + rh*4;
      #pragma unroll
      for(int r=0;r<4;r++){
        float v = acc[i][j][r] + bb;
        if(OUT_BF16) ((unsigned short*)out)[(row+r)*N + col] = f2bf(v);
        else         ((float*)out)[(row+r)*N + col] = v;
      }
    }
  }
}

// ---------- flash attention: block = (b,h,64 q rows), 4 waves x 16 rows, KVB=64 ----------
__global__ __launch_bounds__(256) void k_attn(const unsigned short* __restrict__ QKV,
                                              const unsigned short* __restrict__ Vtg,
                                              unsigned short* __restrict__ Ob){
  const int qt = blockIdx.x, h = blockIdx.y, b = blockIdx.z;
  const int tid = threadIdx.x, lane = tid & 63, w = tid >> 6;
  const int rl = lane & 15, rh = lane >> 4;
  __shared__ unsigned short lK[64*128];     // [kv][d]  xor-swizzled rows (256B pitch)
  __shared__ unsigned short lV[128*64];     // [d][kv]  xor-swizzled rows (128B pitch)
  __shared__ unsigned short lP[4][16*64];   // per-wave P [q][kv] xor-swizzled

  const float scale = 0.08838834764831845f;  // 1/sqrt(128)

  // Q fragments (A-operand), rows qt*64 + w*16 + rl
  const long qrow = (long)b*S_ + qt*64 + w*16 + rl;
  bf16x8 qf[4];
  #pragma unroll
  for(int kk=0;kk<4;kk++)
    qf[kk] = *(const bf16x8*)&QKV[qrow*NQKV + h*HD + kk*32 + rh*8];

  f32x4 oacc[8] = {};
  float mrun[4], lrun[4];
  #pragma unroll
  for(int r=0;r<4;r++){ mrun[r] = -3.0e38f; lrun[r] = 0.f; }

  const unsigned short* Kg = QKV + (long)b*S_*NQKV + H_;        // K cols
  const unsigned short* Vt = Vtg + (long)b*HD*S_;

  for(int kt=0; kt<S_/64; ++kt){
    // stage K tile [64][128]: 1024 16B chunks
    #pragma unroll
    for(int c=0;c<4;c++){
      int cid = tid + c*256;
      int row = cid >> 4, cb = (cid & 15)*16;
      bf16x8 kd = *(const bf16x8*)&Kg[(long)(kt*64+row)*NQKV + (cb>>1)];
      *(bf16x8*)((char*)lK + row*256 + (cb ^ ((row&7)<<4))) = kd;
    }
    // stage V^T tile [128][64] from Vtg (coalesced rows)
    #pragma unroll
    for(int c=0;c<4;c++){
      int cid = tid + c*256;
      int d = cid >> 3, cb = (cid & 7)*16;
      bf16x8 vd = *(const bf16x8*)&Vt[(long)d*S_ + kt*64 + (cb>>1)];
      *(bf16x8*)((char*)lV + d*128 + (cb ^ ((d&7)<<4))) = vd;
    }
    __syncthreads();

    // QK^T -> sc[n0][r] = score[q = rh*4+r][kv = n0*16+rl]
    f32x4 sc[4];
    #pragma unroll
    for(int n0=0;n0<4;n0++){
      f32x4 s = {0.f,0.f,0.f,0.f};
      #pragma unroll
      for(int kk=0;kk<4;kk++){
        int krow = n0*16 + rl;
        bf16x8 kf = *(const bf16x8*)((const char*)lK + krow*256 +
                       (((kk*32 + rh*8)*2) ^ ((krow&7)<<4)));
        s = MFMA(qf[kk], kf, s);
      }
      sc[n0] = s * scale;
    }

    // online softmax
    float mnew[4], resc[4];
    #pragma unroll
    for(int r=0;r<4;r++){
      float mx = fmaxf(fmaxf(sc[0][r],sc[1][r]), fmaxf(sc[2][r],sc[3][r]));
      #pragma unroll
      for(int msk=1; msk<16; msk<<=1) mx = fmaxf(mx, __shfl_xor(mx, msk));
      mnew[r] = fmaxf(mrun[r], mx);
      resc[r] = __expf(mrun[r] - mnew[r]);
      mrun[r] = mnew[r];
    }
    float psum[4] = {0.f,0.f,0.f,0.f};
    #pragma unroll
    for(int n0=0;n0<4;n0++)
      #pragma unroll
      for(int r=0;r<4;r++){
        float p = __expf(sc[n0][r] - mnew[r]);
        sc[n0][r] = p;
        psum[r] += p;
      }
    #pragma unroll
    for(int r=0;r<4;r++){
      float s = psum[r];
      #pragma unroll
      for(int msk=1; msk<16; msk<<=1) s += __shfl_xor(s, msk);
      lrun[r] = lrun[r]*resc[r] + s;
    }
    #pragma unroll
    for(int nd=0;nd<8;nd++){
      f32x4 o = oacc[nd];
      o[0]*=resc[0]; o[1]*=resc[1]; o[2]*=resc[2]; o[3]*=resc[3];
      oacc[nd] = o;
    }

    // P -> per-wave LDS (bf16), swizzled
    #pragma unroll
    for(int n0=0;n0<4;n0++)
      #pragma unroll
      for(int r=0;r<4;r++){
        int q = rh*4 + r;
        int byteoff = q*128 + (n0*16+rl)*2;
        *(unsigned short*)((char*)&lP[w][0] + (byteoff ^ ((q&7)<<4))) = f2bf(sc[n0][r]);
      }

    // PV: O += P @ V
    #pragma unroll
    for(int kk=0;kk<2;kk++){
      bf16x8 pf = *(const bf16x8*)((const char*)&lP[w][0] +
                     ((rl*128 + (kk*32 + rh*8)*2) ^ ((rl&7)<<4)));
      #pragma unroll
      for(int nd=0;nd<8;nd++){
        int d = nd*16 + rl;
        bf16x8 vf = *(const bf16x8*)((const char*)lV +
                       ((d*128 + (kk*32 + rh*8)*2) ^ ((d&7)<<4)));
        oacc[nd] = MFMA(pf, vf, oacc[nd]);
      }
    }
    __syncthreads();
  }

  // normalize + store
  #pragma unroll
  for(int r=0;r<4;r++) lrun[r] = 1.f / lrun[r];
  long orow = (long)b*S_ + qt*64 + w*16 + rh*4;
  #pragma unroll
  for(int nd=0;nd<8;nd++){
    int col = h*HD + nd*16 + rl;
    #pragma unroll
    for(int r=0;r<4;r++)
      Ob[(orow+r)*H_ + col] = f2bf(oacc[nd][r] * lrun[r]);
  }
}

extern "C" void kernel_launch(void* const* d_in, const int* in_sizes, int n_in,
                              void* d_out, int out_size, void* d_ws, size_t ws_size,
                              hipStream_t stream){
  (void)in_sizes; (void)n_in; (void)out_size; (void)ws_size;
  const float* x  = (const float*)d_in[0];
  const float* Wq = (const float*)d_in[1];
  const float* bq = (const float*)d_in[2];
  const float* Wk = (const float*)d_in[3];
  const float* bk = (const float*)d_in[4];
  const float* Wv = (const float*)d_in[5];
  const float* bv = (const float*)d_in[6];
  const float* Wo = (const float*)d_in[7];
  const float* bo = (const float*)d_in[8];
  float* out = (float*)d_out;

  char* wsb = (char*)d_ws;
  size_t off = 0;
  auto alloc = [&](size_t bytes){ void* p = wsb + off; off += (bytes + 255) & ~(size_t)255; return p; };
  unsigned short* xb   = (unsigned short*)alloc((size_t)NR*H_*2);      // 16.8 MB
  unsigned short* Bqkv = (unsigned short*)alloc((size_t)NQKV*H_*2);    //  9.4 MB
  unsigned short* Wot  = (unsigned short*)alloc((size_t)H_*H_*2);      //  8.4 MB
  float*          bqkv = (float*)alloc((size_t)NQKV*4);
  unsigned short* QKV  = (unsigned short*)alloc((size_t)NR*NQKV*2);    // 18.9 MB
  unsigned short* Vtg  = (unsigned short*)alloc((size_t)B_*HD*S_*2);   //  1.0 MB
  unsigned short* Ob   = (unsigned short*)alloc((size_t)NR*H_*2);      // 16.8 MB

  k_convx  <<<NR*H_/1024, 256, 0, stream>>>(x, xb);
  k_transw <<<dim3(64,64), 256, 0, stream>>>(Wq, Bqkv, H_, 0);
  k_transw <<<dim3(4,64),  256, 0, stream>>>(Wk, Bqkv, HD, H_);
  k_transw <<<dim3(4,64),  256, 0, stream>>>(Wv, Bqkv, HD, H_+HD);
  k_transw <<<dim3(64,64), 256, 0, stream>>>(Wo, Wot, H_, 0);
  k_biascat<<<NQKV/256, 256, 0, stream>>>(bq, bk, bv, bqkv);

  k_gemm<1><<<dim3(NQKV/128, NR/128), 256, 0, stream>>>(xb, Bqkv, bqkv, QKV, NR, NQKV, H_);
  k_transv <<<dim3(S_/32, HD/32, B_), 256, 0, stream>>>(QKV, Vtg);
  k_attn   <<<dim3(S_/64, NH, B_), 256, 0, stream>>>(QKV, Vtg, Ob);
  k_gemm<0><<<dim3(H_/128, NR/128), 256, 0, stream>>>(Ob, Wot, bo, out, NR, H_, H_);
}

// Round 3
// 309.076 us; speedup vs baseline: 1.0373x; 1.0373x over previous
//
#include <hip/hip_runtime.h>
#include <stdint.h>

#define H_   2048
#define NH   16
#define HD   128
#define B_   2
#define S_   2048
#define NR   (B_*S_)        // 4096 rows of x
#define NQKV (H_ + 2*HD)    // 2304 fused QKV output cols

typedef __attribute__((ext_vector_type(8))) short bf16x8;
typedef __attribute__((ext_vector_type(4))) float f32x4;
typedef __attribute__((ext_vector_type(16))) float f32x16;
typedef __attribute__((ext_vector_type(4))) unsigned short u16x4;

#define MFMA(a,b,c) __builtin_amdgcn_mfma_f32_16x16x32_bf16(a,b,c,0,0,0)
#define MFMA32(a,b,c) __builtin_amdgcn_mfma_f32_32x32x16_bf16(a,b,c,0,0,0)
#define PLSWAP(a,b) asm("v_permlane32_swap_b32 %0, %1" : "+v"(a), "+v"(b))

__device__ __forceinline__ unsigned short f2bf(float f){
  union{ float f; unsigned int u; } v; v.f = f;
  unsigned int u = v.u;
  return (unsigned short)((u + 0x7fffu + ((u>>16)&1u)) >> 16);
}
__device__ __forceinline__ unsigned int pack2(float lo, float hi){
  return ((unsigned int)f2bf(hi) << 16) | (unsigned int)f2bf(lo);
}

__device__ __forceinline__ void gl_lds16(const void* g, void* l){
  __builtin_amdgcn_global_load_lds((const __attribute__((address_space(1))) void*)g,
                                   (__attribute__((address_space(3))) void*)l, 16, 0, 0);
}

// ---------- fp32 -> bf16 convert (x) ----------
__global__ __launch_bounds__(256) void k_convx(const float* __restrict__ x,
                                               unsigned short* __restrict__ xb){
  long i = ((long)blockIdx.x*256 + threadIdx.x)*4;
  float4 f = *reinterpret_cast<const float4*>(x + i);
  u16x4 o;
  o[0]=f2bf(f.x); o[1]=f2bf(f.y); o[2]=f2bf(f.z); o[3]=f2bf(f.w);
  *reinterpret_cast<u16x4*>(xb + i) = o;
}

// ---------- transpose-convert W [K=2048][N] f32 -> Bt rows [rowoff..rowoff+N) pitch 2048 bf16 ----------
__global__ __launch_bounds__(256) void k_transw(const float* __restrict__ W,
                                                unsigned short* __restrict__ Bt,
                                                int N, int rowoff){
  __shared__ float t[32][33];
  int n0 = blockIdx.x*32, k0 = blockIdx.y*32;
  int tx = threadIdx.x & 31, ty = threadIdx.x >> 5;  // ty 0..7
  #pragma unroll
  for(int r=0;r<32;r+=8) t[ty+r][tx] = W[(long)(k0+ty+r)*N + n0+tx];
  __syncthreads();
  #pragma unroll
  for(int r=0;r<32;r+=8)
    Bt[(long)(rowoff + n0+ty+r)*2048 + k0+tx] = f2bf(t[tx][ty+r]);
}

// ---------- concat bias [bq|bk|bv] -> f32[2304] ----------
__global__ void k_biascat(const float* __restrict__ bq, const float* __restrict__ bk,
                          const float* __restrict__ bv, float* __restrict__ o){
  int t = blockIdx.x*256 + threadIdx.x;
  if(t < H_) o[t] = bq[t];
  else if(t < H_+HD) o[t] = bk[t-H_];
  else o[t] = bv[t-H_-HD];
}

// ---------- bf16 transpose of V columns of QKV -> Vtg [B][128][2048] ----------
__global__ __launch_bounds__(256) void k_transv(const unsigned short* __restrict__ QKV,
                                                unsigned short* __restrict__ Vtg){
  __shared__ unsigned short t[32][33];
  int s0 = blockIdx.x*32, d0 = blockIdx.y*32, z = blockIdx.z;
  int tx = threadIdx.x & 31, ty = threadIdx.x >> 5;
  #pragma unroll
  for(int r=0;r<32;r+=8)
    t[ty+r][tx] = QKV[(long)(z*S_ + s0+ty+r)*NQKV + (H_+HD) + d0+tx];
  __syncthreads();
  #pragma unroll
  for(int r=0;r<32;r+=8)
    Vtg[(long)z*HD*S_ + (long)(d0+ty+r)*S_ + s0+tx] = t[tx][ty+r];
}

// ---------- bf16 GEMM: A[M][K] row-major, Bt[N][K] row-major, +bias, m97-style 128x128 ----------
template<int OUT_BF16>
__global__ __launch_bounds__(256) void k_gemm(const unsigned short* __restrict__ A,
                                              const unsigned short* __restrict__ Bt,
                                              const float* __restrict__ bias,
                                              void* __restrict__ out,
                                              int M, int N, int K){
  __shared__ unsigned short lA[2][128*32];
  __shared__ unsigned short lB[2][128*32];
  const int tid = threadIdx.x, lane = tid & 63, w = tid >> 6;
  const int wr = w >> 1, wc = w & 1;
  const long bm = (long)blockIdx.y*128, bn = (long)blockIdx.x*128;
  const int rl = lane & 15, rh = lane >> 4;
  f32x4 acc[4][4] = {};

  const int srow = lane >> 2;
  const int scb  = (((lane&3) ^ ((lane>>2)&3)) * 8);
  long arow[2], brow[2];
  #pragma unroll
  for(int q=0;q<2;q++){ arow[q] = bm + (w*2+q)*16 + srow; brow[q] = bn + (w*2+q)*16 + srow; }

  const int nk = K >> 5;
  #pragma unroll
  for(int q=0;q<2;q++){
    gl_lds16(A  + arow[q]*K + scb, &lA[0][(w*2+q)*512]);
    gl_lds16(Bt + brow[q]*K + scb, &lB[0][(w*2+q)*512]);
  }
  __syncthreads();

  for(int kt=0; kt<nk; ++kt){
    const int cur = kt & 1;
    if(kt+1 < nk){
      const int k0 = (kt+1) << 5;
      #pragma unroll
      for(int q=0;q<2;q++){
        gl_lds16(A  + arow[q]*K + k0 + scb, &lA[cur^1][(w*2+q)*512]);
        gl_lds16(Bt + brow[q]*K + k0 + scb, &lB[cur^1][(w*2+q)*512]);
      }
    }
    bf16x8 af[4], bfr[4];
    #pragma unroll
    for(int i=0;i<4;i++){
      int ra = wr*64 + i*16 + rl;
      af[i]  = *(const bf16x8*)((const char*)&lA[cur][0] + ra*64 + ((rh*16) ^ ((rl&3)<<4)));
      int rb = wc*64 + i*16 + rl;
      bfr[i] = *(const bf16x8*)((const char*)&lB[cur][0] + rb*64 + ((rh*16) ^ ((rl&3)<<4)));
    }
    #pragma unroll
    for(int i=0;i<4;i++)
      #pragma unroll
      for(int j=0;j<4;j++)
        acc[i][j] = MFMA(af[i], bfr[j], acc[i][j]);
    __syncthreads();
  }

  #pragma unroll
  for(int j=0;j<4;j++){
    long col = bn + wc*64 + j*16 + rl;
    float bb = bias[col];
    #pragma unroll
    for(int i=0;i<4;i++){
      long row = bm + wr*64 + i*16 + rh*4;
      #pragma unroll
      for(int r=0;r<4;r++){
        float v = acc[i][j][r] + bb;
        if(OUT_BF16) ((unsigned short*)out)[(row+r)*N + col] = f2bf(v);
        else         ((float*)out)[(row+r)*N + col] = v;
      }
    }
  }
}

// ---------- flash attention, swapped-QK^T 32x32 structure ----------
// block = (b, h, 128 q rows), 4 warps x 32 q rows, KVB = 64.
// QK^T: mfma(K,Q) -> S^T, col(lane&31)=q, row=crow(r,hi)=kv  -> softmax fully lane-local per q
// PV:   mfma(V^T,P) -> O^T, col=q, row=d ; P-frags built in-register via pack2+permlane32_swap
__global__ __launch_bounds__(256) void k_attn(const unsigned short* __restrict__ QKV,
                                              const unsigned short* __restrict__ Vtg,
                                              unsigned short* __restrict__ Ob){
  const int qt = blockIdx.x, h = blockIdx.y, b = blockIdx.z;
  const int tid = threadIdx.x, lane = tid & 63, w = tid >> 6;
  const int ql = lane & 31, hi = lane >> 5;
  __shared__ char lds[65536];
  // buffer layout: K tile [64][128] bf16 @ cur*16384; V^T tile [128][64] bf16 @ 32768 + cur*16384
  const float C1 = 0.12751746f;                 // (1/sqrt(128)) * log2(e)

  // Q fragments in registers: Q[q=ql][k = kk*16 + hi*8 + j]
  const long qrow = (long)b*S_ + qt*128 + w*32 + ql;
  bf16x8 qf[8];
  #pragma unroll
  for(int kk=0;kk<8;kk++)
    qf[kk] = *(const bf16x8*)&QKV[qrow*NQKV + h*HD + kk*16 + hi*8];

  f32x16 oacc[4] = {};    // O^T accum: col=q(ql), row = d32*32 + crow(r,hi)
  float mrun = -3.0e38f, lrun = 0.f;

  const char* Kg = (const char*)QKV + (long)b*S_*4608 + 4096;   // K panel, row pitch 4608B
  const char* Vt = (const char*)Vtg + (long)b*HD*S_*2;          // V^T, row pitch 4096B

  auto stage = [&](int t, int buf){
    char* kb = lds + buf*16384;
    char* vb = lds + 32768 + buf*16384;
    #pragma unroll
    for(int j=0;j<4;j++){
      int g = j*4 + w;
      int row = g*4 + (lane>>4);   // K: 16 chunks/row
      gl_lds16(Kg + (long)(t*64 + row)*4608 + (((lane&15)*16) ^ ((row&7)<<4)),
               kb + g*1024);
    }
    #pragma unroll
    for(int j=0;j<4;j++){
      int g = j*4 + w;
      int row = g*8 + (lane>>3);   // V^T: 8 chunks/row
      gl_lds16(Vt + (long)row*4096 + t*128 + (((lane&7)*16) ^ ((row&7)<<4)),
               vb + g*1024);
    }
  };

  stage(0, 0);
  __syncthreads();

  for(int kt=0; kt<S_/64; ++kt){
    const int cur = kt & 1;
    if(kt+1 < S_/64) stage(kt+1, cur^1);   // async, lands before next barrier
    const char* kc = lds + cur*16384;
    const char* vc = lds + 32768 + cur*16384;

    // ---- QK^T (swapped): sacc[n] covers kv = n*32 + crow(r,hi), q = ql ----
    f32x16 sacc[2] = {};
    #pragma unroll
    for(int n=0;n<2;n++){
      const int krow = n*32 + ql;
      #pragma unroll
      for(int kk=0;kk<8;kk++){
        bf16x8 kf = *(const bf16x8*)(kc + krow*256 + ((kk*32 + hi*16) ^ ((ql&7)<<4)));
        sacc[n] = MFMA32(kf, qf[kk], sacc[n]);
      }
    }

    // ---- online softmax (lane-local row + one cross-half exchange) ----
    float tmax = sacc[0][0];
    #pragma unroll
    for(int n=0;n<2;n++)
      #pragma unroll
      for(int r=0;r<16;r++) tmax = fmaxf(tmax, sacc[n][r]);
    tmax = fmaxf(tmax, __shfl_xor(tmax, 32));
    const float mnew = fmaxf(mrun, tmax);
    const float rfac = __builtin_exp2f((mrun - mnew)*C1);
    mrun = mnew;
    const float nm = -mnew*C1;
    float lsum = 0.f;
    #pragma unroll
    for(int n=0;n<2;n++)
      #pragma unroll
      for(int r=0;r<16;r++){
        float p = __builtin_exp2f(fmaf(sacc[n][r], C1, nm));
        sacc[n][r] = p; lsum += p;
      }
    lsum += __shfl_xor(lsum, 32);
    lrun = lrun*rfac + lsum;
    #pragma unroll
    for(int d32=0; d32<4; d32++) oacc[d32] *= rfac;

    // ---- P -> bf16 A-row-fragments via pack + permlane32_swap (T12) ----
    bf16x8 pa[4];
    #pragma unroll
    for(int n=0;n<2;n++){
      unsigned int k0m0 = pack2(sacc[n][0],  sacc[n][1]),  k0m1 = pack2(sacc[n][2],  sacc[n][3]);
      unsigned int k1m0 = pack2(sacc[n][4],  sacc[n][5]),  k1m1 = pack2(sacc[n][6],  sacc[n][7]);
      unsigned int k2m0 = pack2(sacc[n][8],  sacc[n][9]),  k2m1 = pack2(sacc[n][10], sacc[n][11]);
      unsigned int k3m0 = pack2(sacc[n][12], sacc[n][13]), k3m1 = pack2(sacc[n][14], sacc[n][15]);
      PLSWAP(k0m0, k1m0); PLSWAP(k0m1, k1m1);
      PLSWAP(k2m0, k3m0); PLSWAP(k2m1, k3m1);
      union { unsigned int u[4]; bf16x8 v; } f0, f1;
      f0.u[0]=k0m0; f0.u[1]=k0m1; f0.u[2]=k1m0; f0.u[3]=k1m1;
      f1.u[0]=k2m0; f1.u[1]=k2m1; f1.u[2]=k3m0; f1.u[3]=k3m1;
      pa[n*2] = f0.v; pa[n*2+1] = f1.v;
    }

    // ---- PV: O^T += V^T . P^T ----
    #pragma unroll
    for(int d32=0; d32<4; d32++){
      const int vrow = d32*32 + ql;
      #pragma unroll
      for(int kk=0;kk<4;kk++){
        bf16x8 vf = *(const bf16x8*)(vc + vrow*128 + ((kk*32 + hi*16) ^ ((ql&7)<<4)));
        oacc[d32] = MFMA32(vf, pa[kk], oacc[d32]);
      }
    }
    __syncthreads();
  }

  // ---- epilogue: per-warp LDS transpose O^T -> O, coalesced store ----
  const float linv = 1.0f / lrun;
  unsigned short* ot = (unsigned short*)(lds) + w*(128*34);   // [128 d][32 q], pitch 34
  #pragma unroll
  for(int d32=0; d32<4; d32++)
    #pragma unroll
    for(int r=0;r<16;r++){
      int d = d32*32 + (r&3) + 8*(r>>2) + 4*hi;
      ot[d*34 + ql] = f2bf(oacc[d32][r]*linv);
    }
  unsigned short* dst = Ob + qrow*H_ + h*HD + hi*64;
  #pragma unroll
  for(int i=0;i<8;i++){
    union { unsigned short s[8]; bf16x8 v; } o;
    #pragma unroll
    for(int e=0;e<8;e++) o.s[e] = ot[(hi*64 + i*8 + e)*34 + ql];
    *(bf16x8*)(dst + i*8) = o.v;
  }
}

extern "C" void kernel_launch(void* const* d_in, const int* in_sizes, int n_in,
                              void* d_out, int out_size, void* d_ws, size_t ws_size,
                              hipStream_t stream){
  (void)in_sizes; (void)n_in; (void)out_size; (void)ws_size;
  const float* x  = (const float*)d_in[0];
  const float* Wq = (const float*)d_in[1];
  const float* bq = (const float*)d_in[2];
  const float* Wk = (const float*)d_in[3];
  const float* bk = (const float*)d_in[4];
  const float* Wv = (const float*)d_in[5];
  const float* bv = (const float*)d_in[6];
  const float* Wo = (const float*)d_in[7];
  const float* bo = (const float*)d_in[8];
  float* out = (float*)d_out;

  char* wsb = (char*)d_ws;
  size_t off = 0;
  auto alloc = [&](size_t bytes){ void* p = wsb + off; off += (bytes + 255) & ~(size_t)255; return p; };
  unsigned short* xb   = (unsigned short*)alloc((size_t)NR*H_*2);
  unsigned short* Bqkv = (unsigned short*)alloc((size_t)NQKV*H_*2);
  unsigned short* Wot  = (unsigned short*)alloc((size_t)H_*H_*2);
  float*          bqkv = (float*)alloc((size_t)NQKV*4);
  unsigned short* QKV  = (unsigned short*)alloc((size_t)NR*NQKV*2);
  unsigned short* Vtg  = (unsigned short*)alloc((size_t)B_*HD*S_*2);
  unsigned short* Ob   = (unsigned short*)alloc((size_t)NR*H_*2);

  k_convx  <<<NR*H_/1024, 256, 0, stream>>>(x, xb);
  k_transw <<<dim3(64,64), 256, 0, stream>>>(Wq, Bqkv, H_, 0);
  k_transw <<<dim3(4,64),  256, 0, stream>>>(Wk, Bqkv, HD, H_);
  k_transw <<<dim3(4,64),  256, 0, stream>>>(Wv, Bqkv, HD, H_+HD);
  k_transw <<<dim3(64,64), 256, 0, stream>>>(Wo, Wot, H_, 0);
  k_biascat<<<NQKV/256, 256, 0, stream>>>(bq, bk, bv, bqkv);

  k_gemm<1><<<dim3(NQKV/128, NR/128), 256, 0, stream>>>(xb, Bqkv, bqkv, QKV, NR, NQKV, H_);
  k_transv <<<dim3(S_/32, HD/32, B_), 256, 0, stream>>>(QKV, Vtg);
  k_attn   <<<dim3(S_/128, NH, B_), 256, 0, stream>>>(QKV, Vtg, Ob);
  k_gemm<0><<<dim3(H_/128, NR/128), 256, 0, stream>>>(Ob, Wot, bo, out, NR, H_, H_);
}

// Round 4
// 271.935 us; speedup vs baseline: 1.1790x; 1.1366x over previous
//
#include <hip/hip_runtime.h>
#include <stdint.h>

#define H_   2048
#define NH   16
#define HD   128
#define B_   2
#define S_   2048
#define NR   (B_*S_)        // 4096 rows of x
#define NQKV (H_ + 2*HD)    // 2304 fused QKV output cols

typedef __attribute__((ext_vector_type(8))) short bf16x8;
typedef __attribute__((ext_vector_type(4))) float f32x4;
typedef __attribute__((ext_vector_type(16))) float f32x16;
typedef __attribute__((ext_vector_type(4))) unsigned short u16x4;

#define MFMA(a,b,c) __builtin_amdgcn_mfma_f32_16x16x32_bf16(a,b,c,0,0,0)
#define MFMA32(a,b,c) __builtin_amdgcn_mfma_f32_32x32x16_bf16(a,b,c,0,0,0)
#define PLSWAP(a,b) asm("v_permlane32_swap_b32 %0, %1" : "+v"(a), "+v"(b))

__device__ __forceinline__ unsigned short f2bf(float f){
  union{ float f; unsigned int u; } v; v.f = f;
  unsigned int u = v.u;
  return (unsigned short)((u + 0x7fffu + ((u>>16)&1u)) >> 16);
}
__device__ __forceinline__ unsigned int cvtpk(float lo, float hi){
  unsigned int r;
  asm("v_cvt_pk_bf16_f32 %0, %1, %2" : "=v"(r) : "v"(lo), "v"(hi));
  return r;
}

__device__ __forceinline__ void gl_lds16(const void* g, void* l){
  __builtin_amdgcn_global_load_lds((const __attribute__((address_space(1))) void*)g,
                                   (__attribute__((address_space(3))) void*)l, 16, 0, 0);
}

// ---------- fp32 -> bf16 convert (x) ----------
__global__ __launch_bounds__(256) void k_convx(const float* __restrict__ x,
                                               unsigned short* __restrict__ xb){
  long i = ((long)blockIdx.x*256 + threadIdx.x)*4;
  float4 f = *reinterpret_cast<const float4*>(x + i);
  u16x4 o;
  o[0]=f2bf(f.x); o[1]=f2bf(f.y); o[2]=f2bf(f.z); o[3]=f2bf(f.w);
  *reinterpret_cast<u16x4*>(xb + i) = o;
}

// ---------- transpose-convert W [K=2048][N] f32 -> Bt rows [rowoff..rowoff+N) pitch 2048 bf16 ----------
__global__ __launch_bounds__(256) void k_transw(const float* __restrict__ W,
                                                unsigned short* __restrict__ Bt,
                                                int N, int rowoff){
  __shared__ float t[32][33];
  int n0 = blockIdx.x*32, k0 = blockIdx.y*32;
  int tx = threadIdx.x & 31, ty = threadIdx.x >> 5;  // ty 0..7
  #pragma unroll
  for(int r=0;r<32;r+=8) t[ty+r][tx] = W[(long)(k0+ty+r)*N + n0+tx];
  __syncthreads();
  #pragma unroll
  for(int r=0;r<32;r+=8)
    Bt[(long)(rowoff + n0+ty+r)*2048 + k0+tx] = f2bf(t[tx][ty+r]);
}

// ---------- concat bias [bq|bk|bv] -> f32[2304] ----------
__global__ void k_biascat(const float* __restrict__ bq, const float* __restrict__ bk,
                          const float* __restrict__ bv, float* __restrict__ o){
  int t = blockIdx.x*256 + threadIdx.x;
  if(t < H_) o[t] = bq[t];
  else if(t < H_+HD) o[t] = bk[t-H_];
  else o[t] = bv[t-H_-HD];
}

// ---------- bf16 transpose of V columns of QKV -> Vtg [B][128][2048] ----------
__global__ __launch_bounds__(256) void k_transv(const unsigned short* __restrict__ QKV,
                                                unsigned short* __restrict__ Vtg){
  __shared__ unsigned short t[32][33];
  int s0 = blockIdx.x*32, d0 = blockIdx.y*32, z = blockIdx.z;
  int tx = threadIdx.x & 31, ty = threadIdx.x >> 5;
  #pragma unroll
  for(int r=0;r<32;r+=8)
    t[ty+r][tx] = QKV[(long)(z*S_ + s0+ty+r)*NQKV + (H_+HD) + d0+tx];
  __syncthreads();
  #pragma unroll
  for(int r=0;r<32;r+=8)
    Vtg[(long)z*HD*S_ + (long)(d0+ty+r)*S_ + s0+tx] = t[tx][ty+r];
}

// ---------- bf16 GEMM: A[M][K] row-major, Bt[N][K] row-major, +bias, m97-style 128x128 ----------
template<int OUT_BF16>
__global__ __launch_bounds__(256) void k_gemm(const unsigned short* __restrict__ A,
                                              const unsigned short* __restrict__ Bt,
                                              const float* __restrict__ bias,
                                              void* __restrict__ out,
                                              int M, int N, int K){
  __shared__ unsigned short lA[2][128*32];
  __shared__ unsigned short lB[2][128*32];
  const int tid = threadIdx.x, lane = tid & 63, w = tid >> 6;
  const int wr = w >> 1, wc = w & 1;
  const long bm = (long)blockIdx.y*128, bn = (long)blockIdx.x*128;
  const int rl = lane & 15, rh = lane >> 4;
  f32x4 acc[4][4] = {};

  const int srow = lane >> 2;
  const int scb  = (((lane&3) ^ ((lane>>2)&3)) * 8);
  long arow[2], brow[2];
  #pragma unroll
  for(int q=0;q<2;q++){ arow[q] = bm + (w*2+q)*16 + srow; brow[q] = bn + (w*2+q)*16 + srow; }

  const int nk = K >> 5;
  #pragma unroll
  for(int q=0;q<2;q++){
    gl_lds16(A  + arow[q]*K + scb, &lA[0][(w*2+q)*512]);
    gl_lds16(Bt + brow[q]*K + scb, &lB[0][(w*2+q)*512]);
  }
  __syncthreads();

  for(int kt=0; kt<nk; ++kt){
    const int cur = kt & 1;
    if(kt+1 < nk){
      const int k0 = (kt+1) << 5;
      #pragma unroll
      for(int q=0;q<2;q++){
        gl_lds16(A  + arow[q]*K + k0 + scb, &lA[cur^1][(w*2+q)*512]);
        gl_lds16(Bt + brow[q]*K + k0 + scb, &lB[cur^1][(w*2+q)*512]);
      }
    }
    bf16x8 af[4], bfr[4];
    #pragma unroll
    for(int i=0;i<4;i++){
      int ra = wr*64 + i*16 + rl;
      af[i]  = *(const bf16x8*)((const char*)&lA[cur][0] + ra*64 + ((rh*16) ^ ((rl&3)<<4)));
      int rb = wc*64 + i*16 + rl;
      bfr[i] = *(const bf16x8*)((const char*)&lB[cur][0] + rb*64 + ((rh*16) ^ ((rl&3)<<4)));
    }
    #pragma unroll
    for(int i=0;i<4;i++)
      #pragma unroll
      for(int j=0;j<4;j++)
        acc[i][j] = MFMA(af[i], bfr[j], acc[i][j]);
    __syncthreads();
  }

  #pragma unroll
  for(int j=0;j<4;j++){
    long col = bn + wc*64 + j*16 + rl;
    float bb = bias[col];
    #pragma unroll
    for(int i=0;i<4;i++){
      long row = bm + wr*64 + i*16 + rh*4;
      #pragma unroll
      for(int r=0;r<4;r++){
        float v = acc[i][j][r] + bb;
        if(OUT_BF16) ((unsigned short*)out)[(row+r)*N + col] = f2bf(v);
        else         ((float*)out)[(row+r)*N + col] = v;
      }
    }
  }
}

// ---------- flash attention, swapped-QK^T 32x32 structure ----------
// block = (b, h, 128 q rows), 4 warps x 32 q rows, KVB = 64.
// QK^T: mfma(K,Q) -> S^T, col(lane&31)=q, row=crow(r,hi)=kv  -> softmax fully lane-local per q
// PV:   mfma(V^T,P) -> O^T, col=q, row=d ; P-frags built in-register via cvt_pk+permlane32_swap
// LDS swizzle: slot ^= (row&7)^((row>>3)&3)  -- row bits [4:3] folded in so the
// conflict set {ql, ql+8, ql+16, ql+24} (same row&7, bank-invariant row pitch) separates.
__global__ __launch_bounds__(256) void k_attn(const unsigned short* __restrict__ QKV,
                                              const unsigned short* __restrict__ Vtg,
                                              unsigned short* __restrict__ Ob){
  const int qt = blockIdx.x, h = blockIdx.y, b = blockIdx.z;
  const int tid = threadIdx.x, lane = tid & 63, w = tid >> 6;
  const int ql = lane & 31, hi = lane >> 5;
  const int swl = (ql & 7) ^ ((ql >> 3) & 3);   // read-side swizzle (same for K and V rows)
  __shared__ char lds[65536];
  const float C1 = 0.12751746f;                 // (1/sqrt(128)) * log2(e)

  // Q fragments in registers: Q[q=ql][k = kk*16 + hi*8 + j]
  const long qrow = (long)b*S_ + qt*128 + w*32 + ql;
  bf16x8 qf[8];
  #pragma unroll
  for(int kk=0;kk<8;kk++)
    qf[kk] = *(const bf16x8*)&QKV[qrow*NQKV + h*HD + kk*16 + hi*8];

  f32x16 oacc[4] = {};    // O^T accum: col=q(ql), row = d32*32 + crow(r,hi)
  float mrun = -3.0e38f, lrun = 0.f;

  const char* Kg = (const char*)QKV + (long)b*S_*4608 + 4096;   // K panel, row pitch 4608B
  const char* Vt = (const char*)Vtg + (long)b*HD*S_*2;          // V^T, row pitch 4096B

  auto stage = [&](int t, int buf){
    char* kb = lds + buf*16384;
    char* vb = lds + 32768 + buf*16384;
    #pragma unroll
    for(int j=0;j<4;j++){
      int g = j*4 + w;
      int row = g*4 + (lane>>4);   // K: 16 chunks/row
      int sw = (row&7) ^ ((row>>3)&3);
      gl_lds16(Kg + (long)(t*64 + row)*4608 + (((lane&15) ^ sw)*16),
               kb + g*1024);
    }
    #pragma unroll
    for(int j=0;j<4;j++){
      int g = j*4 + w;
      int row = g*8 + (lane>>3);   // V^T: 8 chunks/row
      int sw = (row&7) ^ ((row>>3)&3);
      gl_lds16(Vt + (long)row*4096 + t*128 + (((lane&7) ^ sw)*16),
               vb + g*1024);
    }
  };

  stage(0, 0);
  __syncthreads();

  for(int kt=0; kt<S_/64; ++kt){
    const int cur = kt & 1;
    if(kt+1 < S_/64) stage(kt+1, cur^1);   // async, lands before next barrier
    const char* kc = lds + cur*16384;
    const char* vc = lds + 32768 + cur*16384;

    // ---- QK^T (swapped): sacc[n] covers kv = n*32 + crow(r,hi), q = ql ----
    f32x16 sacc[2] = {};
    #pragma unroll
    for(int n=0;n<2;n++){
      const int krow = n*32 + ql;
      #pragma unroll
      for(int kk=0;kk<8;kk++){
        bf16x8 kf = *(const bf16x8*)(kc + krow*256 + ((kk*32 + hi*16) ^ (swl<<4)));
        sacc[n] = MFMA32(kf, qf[kk], sacc[n]);
      }
    }

    // ---- online softmax: tree max, defer-max (T13), tree sum ----
    float t8[8];
    #pragma unroll
    for(int i=0;i<8;i++)
      t8[i] = fmaxf(fmaxf(sacc[0][2*i],sacc[0][2*i+1]),
                    fmaxf(sacc[1][2*i],sacc[1][2*i+1]));
    float tmax = fmaxf(fmaxf(fmaxf(t8[0],t8[1]),fmaxf(t8[2],t8[3])),
                       fmaxf(fmaxf(t8[4],t8[5]),fmaxf(t8[6],t8[7])));
    tmax = fmaxf(tmax, __shfl_xor(tmax, 32));
    if(!__all(tmax - mrun <= 62.74f)){     // 8/C1: P bounded by 2^8
      const float mnew = fmaxf(mrun, tmax);
      const float rfac = __builtin_exp2f((mrun - mnew)*C1);
      mrun = mnew; lrun *= rfac;
      #pragma unroll
      for(int d32=0; d32<4; d32++) oacc[d32] *= rfac;
    }
    const float nm = -mrun*C1;
    float ps[4] = {0.f,0.f,0.f,0.f};
    #pragma unroll
    for(int n=0;n<2;n++)
      #pragma unroll
      for(int r=0;r<16;r++){
        float p = __builtin_exp2f(fmaf(sacc[n][r], C1, nm));
        sacc[n][r] = p; ps[r&3] += p;
      }
    float lsum = (ps[0]+ps[1])+(ps[2]+ps[3]);
    lsum += __shfl_xor(lsum, 32);
    lrun += lsum;

    // ---- P -> bf16 A-row-fragments via v_cvt_pk_bf16_f32 + permlane32_swap (T12) ----
    bf16x8 pa[4];
    #pragma unroll
    for(int n=0;n<2;n++){
      unsigned int k0m0 = cvtpk(sacc[n][0],  sacc[n][1]),  k0m1 = cvtpk(sacc[n][2],  sacc[n][3]);
      unsigned int k1m0 = cvtpk(sacc[n][4],  sacc[n][5]),  k1m1 = cvtpk(sacc[n][6],  sacc[n][7]);
      unsigned int k2m0 = cvtpk(sacc[n][8],  sacc[n][9]),  k2m1 = cvtpk(sacc[n][10], sacc[n][11]);
      unsigned int k3m0 = cvtpk(sacc[n][12], sacc[n][13]), k3m1 = cvtpk(sacc[n][14], sacc[n][15]);
      PLSWAP(k0m0, k1m0); PLSWAP(k0m1, k1m1);
      PLSWAP(k2m0, k3m0); PLSWAP(k2m1, k3m1);
      union { unsigned int u[4]; bf16x8 v; } f0, f1;
      f0.u[0]=k0m0; f0.u[1]=k0m1; f0.u[2]=k1m0; f0.u[3]=k1m1;
      f1.u[0]=k2m0; f1.u[1]=k2m1; f1.u[2]=k3m0; f1.u[3]=k3m1;
      pa[n*2] = f0.v; pa[n*2+1] = f1.v;
    }

    // ---- PV: O^T += V^T . P^T ----
    #pragma unroll
    for(int d32=0; d32<4; d32++){
      const int vrow = d32*32 + ql;
      #pragma unroll
      for(int kk=0;kk<4;kk++){
        bf16x8 vf = *(const bf16x8*)(vc + vrow*128 + ((kk*32 + hi*16) ^ (swl<<4)));
        oacc[d32] = MFMA32(vf, pa[kk], oacc[d32]);
      }
    }
    __syncthreads();
  }

  // ---- epilogue: per-warp LDS transpose O^T -> O, coalesced store ----
  const float linv = 1.0f / lrun;
  unsigned short* ot = (unsigned short*)(lds) + w*(128*34);   // [128 d][32 q], pitch 34
  #pragma unroll
  for(int d32=0; d32<4; d32++)
    #pragma unroll
    for(int r=0;r<16;r++){
      int d = d32*32 + (r&3) + 8*(r>>2) + 4*hi;
      ot[d*34 + ql] = f2bf(oacc[d32][r]*linv);
    }
  unsigned short* dst = Ob + qrow*H_ + h*HD + hi*64;
  #pragma unroll
  for(int i=0;i<8;i++){
    union { unsigned short s[8]; bf16x8 v; } o;
    #pragma unroll
    for(int e=0;e<8;e++) o.s[e] = ot[(hi*64 + i*8 + e)*34 + ql];
    *(bf16x8*)(dst + i*8) = o.v;
  }
}

extern "C" void kernel_launch(void* const* d_in, const int* in_sizes, int n_in,
                              void* d_out, int out_size, void* d_ws, size_t ws_size,
                              hipStream_t stream){
  (void)in_sizes; (void)n_in; (void)out_size; (void)ws_size;
  const float* x  = (const float*)d_in[0];
  const float* Wq = (const float*)d_in[1];
  const float* bq = (const float*)d_in[2];
  const float* Wk = (const float*)d_in[3];
  const float* bk = (const float*)d_in[4];
  const float* Wv = (const float*)d_in[5];
  const float* bv = (const float*)d_in[6];
  const float* Wo = (const float*)d_in[7];
  const float* bo = (const float*)d_in[8];
  float* out = (float*)d_out;

  char* wsb = (char*)d_ws;
  size_t off = 0;
  auto alloc = [&](size_t bytes){ void* p = wsb + off; off += (bytes + 255) & ~(size_t)255; return p; };
  unsigned short* xb   = (unsigned short*)alloc((size_t)NR*H_*2);
  unsigned short* Bqkv = (unsigned short*)alloc((size_t)NQKV*H_*2);
  unsigned short* Wot  = (unsigned short*)alloc((size_t)H_*H_*2);
  float*          bqkv = (float*)alloc((size_t)NQKV*4);
  unsigned short* QKV  = (unsigned short*)alloc((size_t)NR*NQKV*2);
  unsigned short* Vtg  = (unsigned short*)alloc((size_t)B_*HD*S_*2);
  unsigned short* Ob   = (unsigned short*)alloc((size_t)NR*H_*2);

  k_convx  <<<NR*H_/1024, 256, 0, stream>>>(x, xb);
  k_transw <<<dim3(64,64), 256, 0, stream>>>(Wq, Bqkv, H_, 0);
  k_transw <<<dim3(4,64),  256, 0, stream>>>(Wk, Bqkv, HD, H_);
  k_transw <<<dim3(4,64),  256, 0, stream>>>(Wv, Bqkv, HD, H_+HD);
  k_transw <<<dim3(64,64), 256, 0, stream>>>(Wo, Wot, H_, 0);
  k_biascat<<<NQKV/256, 256, 0, stream>>>(bq, bk, bv, bqkv);

  k_gemm<1><<<dim3(NQKV/128, NR/128), 256, 0, stream>>>(xb, Bqkv, bqkv, QKV, NR, NQKV, H_);
  k_transv <<<dim3(S_/32, HD/32, B_), 256, 0, stream>>>(QKV, Vtg);
  k_attn   <<<dim3(S_/128, NH, B_), 256, 0, stream>>>(QKV, Vtg, Ob);
  k_gemm<0><<<dim3(H_/128, NR/128), 256, 0, stream>>>(Ob, Wot, bo, out, NR, H_, H_);
}